// Round 2
// baseline (14444.786 us; speedup 1.0000x reference)
//
#include <hip/hip_runtime.h>

// R2: persistent cooperative kernel. 256 blocks x 256 thr, weights LDS-resident,
// grid barrier per timestep, 4-stage pipeline XP0 -> L0rec -> XP1 -> L1rec.
// Cell state in registers. Dynamic LDS 148992 B (needs hipFuncSetAttribute).

#define BATCH 128
#define SEQ   256
#define IDIM  512
#define HDIM  768
#define G4    3072
#define NBLK  256
#define NPHASE (SEQ + 3)
#define WSTR  776      // 768 + 8 pad (bf16 elems) -> 1552B row stride, 16B aligned
#define W0STR 520      // 512 + 8 pad
#define HSLOT (BATCH * HDIM)

typedef __bf16 bf16;
typedef __bf16 bf16x8 __attribute__((ext_vector_type(8)));
typedef float  f32x4  __attribute__((ext_vector_type(4)));

__device__ __forceinline__ float sigf(float x){ return 1.f/(1.f + __expf(-x)); }
__device__ __forceinline__ float tanhf_(float x){ return 1.f - 2.f/(1.f + __expf(2.f*x)); }
__device__ __forceinline__ f32x4 mfma16(bf16x8 a, bf16x8 b, f32x4 c){
  return __builtin_amdgcn_mfma_f32_16x16x32_bf16(a, b, c, 0, 0, 0);
}

// ---- prep kernels -------------------------------------------------------

__global__ void convert_x_k(const float* __restrict__ x, bf16* __restrict__ xb){
  long i = ((long)blockIdx.x*256 + threadIdx.x)*8;
  float4 a = *(const float4*)(x+i);
  float4 b = *(const float4*)(x+i+4);
  bf16x8 o;
  o[0]=(bf16)a.x; o[1]=(bf16)a.y; o[2]=(bf16)a.z; o[3]=(bf16)a.w;
  o[4]=(bf16)b.x; o[5]=(bf16)b.y; o[6]=(bf16)b.z; o[7]=(bf16)b.w;
  *(bf16x8*)(xb+i) = o;
}

// dst[c][k] = src[k][oc(c)], c-permutation: c = jhi*64 + gate*16 + jlo
__global__ void build_wp_k(const float* __restrict__ src, bf16* __restrict__ dst, int K){
  int idx = blockIdx.x*256 + threadIdx.x;
  int c = idx / K, k = idx - c*K;
  int oc = ((c>>4)&3)*HDIM + (((c>>6)<<4) | (c&15));
  dst[idx] = (bf16)src[(size_t)k*G4 + oc];
}

__global__ void build_bias_k(const float* __restrict__ bx, const float* __restrict__ bh,
                             float* __restrict__ bc){
  int c = blockIdx.x*256 + threadIdx.x;
  int oc = ((c>>4)&3)*HDIM + (((c>>6)<<4) | (c&15));
  bc[c] = bx[oc] + bh[oc];
}

// ---- persistent kernel --------------------------------------------------

struct PA {
  const bf16* xb;          // [B][S][I]
  const bf16* whp[4];      // role 0=L0f,1=L0b,2=L1f,3=L1b : [3072][768]
  const bf16* wx1p[2];     // dir f,b : [3072][768]
  const bf16* wx0p[2];     // dir f,b : [3072][512]
  const float* biasp[4];   // [3072]
  float* p0[2];            // dir : [2 slots][3072][128]  (P^T, fp32)
  float* p1[2];
  bf16* h0r[2];            // dir : [2 slots][128][768]
  bf16* h1r[2];
  const bf16* zeros;       // [128][768]
  unsigned* bar;
  float* out; float* hn; float* cn;
};

__device__ __forceinline__ void gridbar(unsigned* bar, int phase){
  __syncthreads();
  if (threadIdx.x == 0){
    __threadfence();
    __hip_atomic_fetch_add(bar, 1u, __ATOMIC_ACQ_REL, __HIP_MEMORY_SCOPE_AGENT);
    const unsigned tgt = (unsigned)(NBLK * phase);
    while (__hip_atomic_load(bar, __ATOMIC_ACQUIRE, __HIP_MEMORY_SCOPE_AGENT) < tgt)
      __builtin_amdgcn_s_sleep(2);
    __threadfence();
  }
  __syncthreads();
}

__launch_bounds__(256, 1)
__global__ void lstm_persist(PA a){
  extern __shared__ __align__(16) char smem[];
  const int tid = threadIdx.x;
  const int bx  = blockIdx.x;
  const int w   = tid >> 6;
  const int lane = tid & 63;
  const int l15 = lane & 15, q = lane >> 4;

  if (bx < 192){
    // ---------------- rec block: 64 gate-cols of (layer,dir) + XP0 chunk ----
    const int role = bx / 48, g = bx - role*48;
    const int layer = role >> 1, dir = role & 1;
    const int colbase = g * 64;
    bf16* wlds  = (bf16*)smem;                                   // [64][WSTR]
    bf16* w0lds = (bf16*)(smem + 64*WSTR*2);                     // [32][W0STR]
    bf16* hlds  = (bf16*)(smem + 64*WSTR*2 + 32*W0STR*2) + w*512;// [32][16]/wave

    { const bf16* src = a.whp[role] + (size_t)colbase * HDIM;
      for (int i = tid; i < 64*HDIM/8; i += 256){
        int r = i/96, k8 = i - r*96;
        *(bf16x8*)(wlds + r*WSTR + k8*8) = *(const bf16x8*)(src + (size_t)r*HDIM + k8*8);
      }
      const int chunk0 = g + layer*48;
      const bf16* s0 = a.wx0p[dir] + (size_t)chunk0 * (32*IDIM);
      for (int i = tid; i < 32*IDIM/8; i += 256){
        int r = i/64, k8 = i - r*64;
        *(bf16x8*)(w0lds + r*W0STR + k8*8) = *(const bf16x8*)(s0 + (size_t)r*IDIM + k8*8);
      }
    }
    __syncthreads();

    float bias4[4];
#pragma unroll
    for (int n=0;n<4;++n) bias4[n] = a.biasp[role][colbase + n*16 + l15];
    float cst[8];
#pragma unroll
    for (int i=0;i<8;++i) cst[i] = 0.f;

    bf16* hr = layer ? a.h1r[dir] : a.h0r[dir];
    float* pring = layer ? a.p1[dir] : a.p0[dir];
    float* p0out = a.p0[dir];
    const int c0 = (g + layer*48) * 32;
    const int hnidx = layer + dir*2;
    const int row_lo = w*32 + l15;
    const int rb = w*32 + q*4;

    for (int kk = 0; kk < NPHASE; ++kk){
      if (kk) gridbar(a.bar, kk);

      const int t = kk - (layer ? 3 : 1);
      if (t >= 0 && t < SEQ){
        const bf16* hprev = (t == 0) ? a.zeros : (hr + (size_t)((t-1)&1) * HSLOT);
        const bf16* ar0 = hprev + (size_t)row_lo * HDIM + q*8;
        const bf16* ar1 = ar0 + 16*HDIM;
        f32x4 acc[2][4];
#pragma unroll
        for (int m=0;m<2;++m)
#pragma unroll
          for (int n=0;n<4;++n) acc[m][n] = (f32x4){0.f,0.f,0.f,0.f};

        bf16x8 a0 = *(const bf16x8*)(ar0);
        bf16x8 a1 = *(const bf16x8*)(ar1);
        for (int ks = 0; ks < 24; ++ks){
          const int kn = ks < 23 ? ks+1 : 23;
          bf16x8 n0 = *(const bf16x8*)(ar0 + kn*32);
          bf16x8 n1 = *(const bf16x8*)(ar1 + kn*32);
          const bf16* wb = wlds + ks*32 + q*8;
#pragma unroll
          for (int n=0;n<4;++n){
            bf16x8 bv = *(const bf16x8*)(wb + (n*16 + l15)*WSTR);
            acc[0][n] = mfma16(a0, bv, acc[0][n]);
            acc[1][n] = mfma16(a1, bv, acc[1][n]);
          }
          a0 = n0; a1 = n1;
        }

        const float* pin = pring + (size_t)(t&1) * (G4*BATCH);
        bf16* hout = hr + (size_t)(t&1) * HSLOT;
        const int tout = dir ? (SEQ-1-t) : t;
#pragma unroll
        for (int m=0;m<2;++m){
          const int r0 = rb + m*16;
          f32x4 pv[4];
#pragma unroll
          for (int n=0;n<4;++n)
            pv[n] = *(const f32x4*)(pin + (size_t)(colbase + n*16 + l15)*BATCH + r0);
#pragma unroll
          for (int r=0;r<4;++r){
            const int b = r0 + r;
            float fg = acc[m][0][r] + pv[0][r] + bias4[0];
            float ig = acc[m][1][r] + pv[1][r] + bias4[1];
            float gg = acc[m][2][r] + pv[2][r] + bias4[2];
            float og = acc[m][3][r] + pv[3][r] + bias4[3];
            float c  = sigf(fg)*cst[m*4+r] + sigf(ig)*tanhf_(gg);
            float h  = sigf(og)*tanhf_(c);
            cst[m*4+r] = c;
            hlds[(m*16 + q*4 + r)*16 + l15] = (bf16)h;
            if (layer)
              a.out[(size_t)b*(SEQ*2*HDIM) + (size_t)tout*(2*HDIM) + dir*HDIM + g*16 + l15] = h;
            if (t == SEQ-1){
              a.hn[(size_t)hnidx*HSLOT + (size_t)b*HDIM + g*16 + l15] = h;
              a.cn[(size_t)hnidx*HSLOT + (size_t)b*HDIM + g*16 + l15] = c;
            }
          }
        }
        __syncthreads();
        { const int hrow = w*32 + (lane>>1);
          const int half = lane & 1;
          bf16x8 hv = *(const bf16x8*)(hlds + (lane>>1)*16 + half*8);
          *(bf16x8*)(hout + (size_t)hrow*HDIM + g*16 + half*8) = hv;
        }
      }

      if (kk < SEQ){
        const int t0 = kk;
        const int ts = dir ? (SEQ-1-t0) : t0;
        const bf16* xr0 = a.xb + (size_t)row_lo*(SEQ*IDIM) + (size_t)ts*IDIM + q*8;
        const bf16* xr1 = xr0 + (size_t)16*(SEQ*IDIM);
        f32x4 acc0[2][2];
#pragma unroll
        for (int m=0;m<2;++m)
#pragma unroll
          for (int n=0;n<2;++n) acc0[m][n] = (f32x4){0.f,0.f,0.f,0.f};
        bf16x8 a0 = *(const bf16x8*)(xr0);
        bf16x8 a1 = *(const bf16x8*)(xr1);
        for (int ks = 0; ks < 16; ++ks){
          const int kn = ks < 15 ? ks+1 : 15;
          bf16x8 n0 = *(const bf16x8*)(xr0 + kn*32);
          bf16x8 n1 = *(const bf16x8*)(xr1 + kn*32);
          const bf16* wb = w0lds + ks*32 + q*8;
#pragma unroll
          for (int n=0;n<2;++n){
            bf16x8 bv = *(const bf16x8*)(wb + (n*16 + l15)*W0STR);
            acc0[0][n] = mfma16(a0, bv, acc0[0][n]);
            acc0[1][n] = mfma16(a1, bv, acc0[1][n]);
          }
          a0 = n0; a1 = n1;
        }
        float* pout = p0out + (size_t)(t0&1)*(G4*BATCH);
#pragma unroll
        for (int m=0;m<2;++m)
#pragma unroll
          for (int n=0;n<2;++n)
            *(f32x4*)(pout + (size_t)(c0 + n*16 + l15)*BATCH + rb + m*16) = acc0[m][n];
      }
    }
  } else {
    // ---------------- XP1 block: 96 cols of Wx1[dir] ----
    const int dir = (bx - 192) >> 5, ii = (bx - 192) & 31;
    const int c0 = ii * 96;
    bf16* wlds = (bf16*)smem;   // [96][WSTR]
    { const bf16* src = a.wx1p[dir] + (size_t)c0 * HDIM;
      for (int i = tid; i < 96*HDIM/8; i += 256){
        int r = i/96, k8 = i - r*96;
        *(bf16x8*)(wlds + r*WSTR + k8*8) = *(const bf16x8*)(src + (size_t)r*HDIM + k8*8);
      }
    }
    __syncthreads();
    const bf16* hbase = a.h0r[dir];
    float* pbase = a.p1[dir];
    const int row_lo = w*32 + l15, rb = w*32 + q*4;

    for (int kk = 0; kk < NPHASE; ++kk){
      if (kk) gridbar(a.bar, kk);
      const int t = kk - 2;
      if (t >= 0 && t < SEQ){
        const bf16* hp = hbase + (size_t)(t&1)*HSLOT;
        const bf16* ar0 = hp + (size_t)row_lo*HDIM + q*8;
        const bf16* ar1 = ar0 + 16*HDIM;
        f32x4 acc[2][6];
#pragma unroll
        for (int m=0;m<2;++m)
#pragma unroll
          for (int n=0;n<6;++n) acc[m][n] = (f32x4){0.f,0.f,0.f,0.f};
        bf16x8 a0 = *(const bf16x8*)(ar0);
        bf16x8 a1 = *(const bf16x8*)(ar1);
        for (int ks = 0; ks < 24; ++ks){
          const int kn = ks < 23 ? ks+1 : 23;
          bf16x8 n0 = *(const bf16x8*)(ar0 + kn*32);
          bf16x8 n1 = *(const bf16x8*)(ar1 + kn*32);
          const bf16* wb = wlds + ks*32 + q*8;
#pragma unroll
          for (int n=0;n<6;++n){
            bf16x8 bv = *(const bf16x8*)(wb + (n*16 + l15)*WSTR);
            acc[0][n] = mfma16(a0, bv, acc[0][n]);
            acc[1][n] = mfma16(a1, bv, acc[1][n]);
          }
          a0 = n0; a1 = n1;
        }
        float* pout = pbase + (size_t)(t&1)*(G4*BATCH);
#pragma unroll
        for (int m=0;m<2;++m)
#pragma unroll
          for (int n=0;n<6;++n)
            *(f32x4*)(pout + (size_t)(c0 + n*16 + l15)*BATCH + rb + m*16) = acc[m][n];
      }
    }
  }
}

// ---- host ---------------------------------------------------------------

extern "C" void kernel_launch(void* const* d_in, const int* in_sizes, int n_in,
                              void* d_out, int out_size, void* d_ws, size_t ws_size,
                              hipStream_t stream){
  (void)in_sizes; (void)n_in; (void)out_size; (void)ws_size;
  const float* x = (const float*)d_in[0];
  const float* Wx[4]; const float* bxp[4]; const float* Whp[4]; const float* bhp[4];
  for (int t=0; t<4; ++t){               // tag order: f0, f1, b0, b1
    Wx[t]  = (const float*)d_in[1 + 4*t];
    bxp[t] = (const float*)d_in[2 + 4*t];
    Whp[t] = (const float*)d_in[3 + 4*t];
    bhp[t] = (const float*)d_in[4 + 4*t];
  }
  const int roletag[4] = {0, 2, 1, 3};   // role L0f,L0b,L1f,L1b -> tag f0,b0,f1,b1

  char* ws = (char*)d_ws;
  size_t off = 0;
  auto take = [&](size_t bytes)->char*{ char* p = ws + off; off += (bytes + 255) & ~(size_t)255; return p; };

  bf16* xb = (bf16*)take((size_t)BATCH*SEQ*IDIM*2);
  PA a;
  a.xb = xb;
  bf16* whp_w[4]; for (int r=0;r<4;++r){ whp_w[r] = (bf16*)take((size_t)G4*HDIM*2); a.whp[r] = whp_w[r]; }
  bf16* wx1_w[2]; for (int d=0;d<2;++d){ wx1_w[d] = (bf16*)take((size_t)G4*HDIM*2); a.wx1p[d] = wx1_w[d]; }
  bf16* wx0_w[2]; for (int d=0;d<2;++d){ wx0_w[d] = (bf16*)take((size_t)G4*IDIM*2); a.wx0p[d] = wx0_w[d]; }
  float* bias_w[4]; for (int r=0;r<4;++r){ bias_w[r] = (float*)take((size_t)G4*4); a.biasp[r] = bias_w[r]; }
  for (int d=0;d<2;++d) a.p0[d] = (float*)take((size_t)2*G4*BATCH*4);
  for (int d=0;d<2;++d) a.p1[d] = (float*)take((size_t)2*G4*BATCH*4);
  for (int d=0;d<2;++d) a.h0r[d] = (bf16*)take((size_t)2*BATCH*HDIM*2);
  for (int d=0;d<2;++d) a.h1r[d] = (bf16*)take((size_t)2*BATCH*HDIM*2);
  bf16* zeros = (bf16*)take((size_t)BATCH*HDIM*2);
  a.zeros = zeros;
  a.bar = (unsigned*)take(256);

  // zeros + bar are contiguous (zeros size is a multiple of 256)
  hipMemsetAsync(zeros, 0, (size_t)BATCH*HDIM*2 + 256, stream);

  convert_x_k<<<dim3((BATCH*SEQ*IDIM)/(8*256)), dim3(256), 0, stream>>>(x, xb);
  for (int r=0;r<4;++r)
    build_wp_k<<<dim3(G4*HDIM/256), dim3(256), 0, stream>>>(Whp[roletag[r]], whp_w[r], HDIM);
  build_wp_k<<<dim3(G4*HDIM/256), dim3(256), 0, stream>>>(Wx[1], wx1_w[0], HDIM);  // f1
  build_wp_k<<<dim3(G4*HDIM/256), dim3(256), 0, stream>>>(Wx[3], wx1_w[1], HDIM);  // b1
  build_wp_k<<<dim3(G4*IDIM/256), dim3(256), 0, stream>>>(Wx[0], wx0_w[0], IDIM);  // f0
  build_wp_k<<<dim3(G4*IDIM/256), dim3(256), 0, stream>>>(Wx[2], wx0_w[1], IDIM);  // b0
  for (int r=0;r<4;++r)
    build_bias_k<<<dim3(G4/256), dim3(256), 0, stream>>>(bxp[roletag[r]], bhp[roletag[r]], bias_w[r]);

  a.out = (float*)d_out;
  a.hn  = a.out + (size_t)BATCH*SEQ*2*HDIM;
  a.cn  = a.hn + (size_t)4*BATCH*HDIM;

  const unsigned smem_bytes = 96*WSTR*2;   // 148992: max(rec 136704, xp1 148992)
  hipFuncSetAttribute((const void*)lstm_persist, hipFuncAttributeMaxDynamicSharedMemorySize, smem_bytes);
  void* kargs[] = { &a };
  hipLaunchCooperativeKernel((void*)lstm_persist, dim3(NBLK), dim3(256), kargs, smem_bytes, stream);
}